// Round 8
// baseline (736.133 us; speedup 1.0000x reference)
//
#include <hip/hip_runtime.h>

// VQ: N=262144 vectors (64x4096), D=64, K=512 codewords, fp32.
// out (float32): quantized[16777216] | indices[262144] (as float) | loss[1]
//
// R16 = best-of recombination at R10's proven residency point + T14 prefetch.
//  Evidence:
//   - R15: 512-thr blocks pinned at ~1 block/CU (22% occ) REGARDLESS of LDS
//     (74->22 KB moved 155->147 only). 512-thr shape compiles clean
//     (FETCH 66 / WRITE 70 MB, VGPR 64).
//   - R10: 256-thr, 38 KB, 3 blocks/CU, 37% occ -> 124 us BEST scan, but
//     +83 MB write amplification (strided epilogue).
//   - R14: 256-thr spill correlate = accA/accB double chain (32 live acc).
//  R16: 256-thr blocks, grid 2048, BROWS=128, CHUNK=128 (4 chunks, 38 KB
//  -> 3 blocks/CU), cw_hl pure-copy staging, SINGLE acc chain, R15 dense
//  epilogue + fused exact-fp32 fixup. NEW: async-stage split (T14) --
//  next chunk's 8x16B global loads issued into regs BEFORE compute,
//  ds_written after the following barrier; HBM latency hides under MFMA.
// Verified-correct conventions (R8-R15 absmax 0):
//   A-frag: A[m=lane&15][k=quad*8+j]; B-frag: B[n=lane&15][k=quad*8+j];
//   C/D:    col=lane&15 (codeword), row=quad*4+reg (x-row).

typedef _Float16 half8 __attribute__((ext_vector_type(8)));
typedef float    floatx4 __attribute__((ext_vector_type(4)));

#define NVEC  262144
#define DDIM  64
#define KCW   512
#define LOSS_SCALE (0.25f / 16777216.0f)
#define DMARGIN 0.005f
#define BROWS 128
#define NBLK  (NVEC / BROWS)     // 2048
#define CHUNK 128                // codewords per LDS chunk (4 chunks)

// d_ws layout (re-poisoned every call -> prep rewrites everything):
#define WS_CSQ   0          // f32[512]
#define WS_CSQH  2048       // f32[512]  (0.5*csq)
#define WS_HL    8192       // f16[512*128]: row n = hi[64] | lo[64] (256 B)

__global__ void prep_kernel(const float* __restrict__ cw,
                            float* __restrict__ csq,
                            float* __restrict__ csqh,
                            _Float16* __restrict__ cw_hl,
                            float* __restrict__ loss_slot) {
    int n = blockIdx.x * blockDim.x + threadIdx.x;
    if (n < KCW) {
        const float4* r = (const float4*)(cw + n * DDIM);
        _Float16* orow = cw_hl + n * 128;
        float s = 0.f;
        #pragma unroll
        for (int t = 0; t < 8; ++t) {
            float4 a = r[2 * t], b = r[2 * t + 1];
            half8 hh, ll;
            #pragma unroll
            for (int i = 0; i < 4; ++i) {
                float v = ((const float*)&a)[i];
                s += v * v;
                _Float16 h = (_Float16)v;
                hh[i] = h; ll[i] = (_Float16)(v - (float)h);
                v = ((const float*)&b)[i];
                s += v * v;
                h = (_Float16)v;
                hh[4 + i] = h; ll[4 + i] = (_Float16)(v - (float)h);
            }
            *(half8*)(orow + 8 * t) = hh;
            *(half8*)(orow + 64 + 8 * t) = ll;
        }
        csq[n]  = s;
        csqh[n] = 0.5f * s;
    }
    if (n == 0) *loss_slot = 0.f;
}

__global__ __launch_bounds__(256, 4)
void vq_mfma_kernel(const float* __restrict__ x,
                    const float* __restrict__ cw,
                    const _Float16* __restrict__ cw_hl,
                    const float* __restrict__ csqh,
                    const float* __restrict__ csq,
                    float* __restrict__ out_q,
                    float* __restrict__ out_idx,
                    float* __restrict__ out_loss) {
    __shared__ _Float16      Bs[CHUNK * 136];   // 34816 B: [cw][hi64|lo64] pad
    __shared__ float         csqhs[KCW];        // 2048 B (negated 0.5*csq)
    __shared__ int           win[BROWS];
    __shared__ int           lslist[BROWS];
    __shared__ unsigned char flg[BROWS];
    __shared__ float         red[4];
    __shared__ unsigned      lcnt;

    const int tid  = threadIdx.x;
    const int w    = tid >> 6;
    const int lane = tid & 63;
    const int quad = lane >> 4;
    const int col  = lane & 15;
    const int blk  = blockIdx.x * BROWS;

    if (tid == 0) lcnt = 0u;
    csqhs[tid]       = -csqh[tid];
    csqhs[tid + 256] = -csqh[tid + 256];

    // ---- a-frags: 2 row-tiles/wave (32 rows), hi/lo split, in-register ----
    half8 ah0[2], ah1[2], al0[2], al1[2];
    #pragma unroll
    for (int rt = 0; rt < 2; ++rt) {
        const float* xr = x + (size_t)(blk + w * 32 + rt * 16 + col) * DDIM;
        float4 f0 = *(const float4*)(xr + quad * 8);
        float4 f1 = *(const float4*)(xr + quad * 8 + 4);
        float4 g0 = *(const float4*)(xr + 32 + quad * 8);
        float4 g1 = *(const float4*)(xr + 32 + quad * 8 + 4);
        #pragma unroll
        for (int i = 0; i < 4; ++i) {
            float v = ((const float*)&f0)[i];
            _Float16 h = (_Float16)v;
            ah0[rt][i] = h; al0[rt][i] = (_Float16)(v - (float)h);
            v = ((const float*)&f1)[i]; h = (_Float16)v;
            ah0[rt][4 + i] = h; al0[rt][4 + i] = (_Float16)(v - (float)h);
            v = ((const float*)&g0)[i]; h = (_Float16)v;
            ah1[rt][i] = h; al1[rt][i] = (_Float16)(v - (float)h);
            v = ((const float*)&g1)[i]; h = (_Float16)v;
            ah1[rt][4 + i] = h; al1[rt][4 + i] = (_Float16)(v - (float)h);
        }
    }

    float M1[8], M2[8];
    int   idx[8];
    #pragma unroll
    for (int s = 0; s < 8; ++s) {
        M1[s] = -3.402823466e38f; M2[s] = -3.402823466e38f; idx[s] = 0;
    }

    // ---- scan 512 codewords in 4 LDS chunks of 128, T14 async staging ----
    // thread copies 128 B of pre-split row data: nl = tid>>1, half hh = tid&1
    const int nl = tid >> 1;
    const int hh = tid & 1;
    half8 G[8];                                  // in-flight stage block
    {
        const half8* g = (const half8*)(cw_hl + ((size_t)nl << 7) + (hh << 6));
        #pragma unroll
        for (int b = 0; b < 8; ++b) G[b] = g[b];
    }
    for (int ch = 0; ch < 4; ++ch) {
        __syncthreads();   // all waves done computing prior chunk (iter 0:
                           // covers csqhs/lcnt writes)
        {                  // ds_write staged regs (vmcnt auto-inserted)
            half8* dst = (half8*)&Bs[nl * 136 + hh * 64];
            #pragma unroll
            for (int b = 0; b < 8; ++b) dst[b] = G[b];
        }
        __syncthreads();
        if (ch < 3) {      // issue next chunk's loads; hides under compute
            const half8* g = (const half8*)
                (cw_hl + ((size_t)((ch + 1) * CHUNK + nl) << 7) + (hh << 6));
            #pragma unroll
            for (int b = 0; b < 8; ++b) G[b] = g[b];
        }

        for (int t = 0; t < 8; ++t) {
            const int n  = ch * CHUNK + t * 16 + col;
            const int nb = (t * 16 + col) * 136;
            half8 bh0 = *(const half8*)&Bs[nb + quad * 8];
            half8 bh1 = *(const half8*)&Bs[nb + 32 + quad * 8];
            half8 bl0 = *(const half8*)&Bs[nb + 64 + quad * 8];
            half8 bl1 = *(const half8*)&Bs[nb + 96 + quad * 8];
            const float vn = csqhs[n];                   // = -0.5*csq[n]

            #pragma unroll
            for (int rt = 0; rt < 2; ++rt) {
                floatx4 acc = {vn, vn, vn, vn};          // bias folded into C
                acc = __builtin_amdgcn_mfma_f32_16x16x32_f16(ah0[rt], bh0, acc, 0, 0, 0);
                acc = __builtin_amdgcn_mfma_f32_16x16x32_f16(ah1[rt], bh1, acc, 0, 0, 0);
                acc = __builtin_amdgcn_mfma_f32_16x16x32_f16(al0[rt], bh0, acc, 0, 0, 0);
                acc = __builtin_amdgcn_mfma_f32_16x16x32_f16(al1[rt], bh1, acc, 0, 0, 0);
                acc = __builtin_amdgcn_mfma_f32_16x16x32_f16(ah0[rt], bl0, acc, 0, 0, 0);
                acc = __builtin_amdgcn_mfma_f32_16x16x32_f16(ah1[rt], bl1, acc, 0, 0, 0);
                #pragma unroll
                for (int reg = 0; reg < 4; ++reg) {
                    int s = rt * 4 + reg;
                    float d = acc[reg];                  // dot - 0.5*csq (max)
                    if (d > M1[s]) idx[s] = n;           // strict >: first-max
                    M2[s] = __builtin_amdgcn_fmed3f(M1[s], M2[s], d);
                    M1[s] = fmaxf(M1[s], d);
                }
            }
        }
    }

    // ---- cross-lane (M1, idx, M2) reduce over the 16 cols of each quad ----
    #pragma unroll
    for (int off = 1; off < 16; off <<= 1) {
        #pragma unroll
        for (int s = 0; s < 8; ++s) {
            float o1 = __shfl_xor(M1[s], off, 16);
            float o2 = __shfl_xor(M2[s], off, 16);
            int   oi = __shfl_xor(idx[s], off, 16);
            float mn = fminf(M1[s], o1);             // loser of the two leaders
            M2[s] = fmaxf(fmaxf(M2[s], o2), mn);
            if (o1 > M1[s] || (o1 == M1[s] && oi < idx[s])) idx[s] = oi;
            M1[s] = fmaxf(M1[s], o1);
        }
    }

    // ---- phase A: winners, flags, block-local flagged list ----
    if (col < 4) {   // lane col handles reg=col for both row-tiles
        #pragma unroll
        for (int rt = 0; rt < 2; ++rt) {
            int s  = rt * 4 + col;
            int rl = w * 32 + rt * 16 + quad * 4 + col;
            int nw = idx[s];
            int f  = (M1[s] - M2[s] <= DMARGIN) ? 1 : 0;
            win[rl] = nw;
            flg[rl] = (unsigned char)f;
            out_idx[blk + rl] = (float)nw;           // flagged rows fixed below
            if (f) { unsigned p = atomicAdd(&lcnt, 1u); lslist[p] = rl; }
        }
    }
    __syncthreads();

    // ---- phase B: dense quantized write + commitment loss (skip flagged) ----
    float ls = 0.f;
    #pragma unroll
    for (int k = 0; k < 8; ++k) {
        int rl = k * 16 + (tid >> 4);
        int e4 = (tid & 15) * 4;                     // lane-contiguous 16 B
        int wn = win[rl];
        int f  = flg[rl];
        float4 q  = *(const float4*)(cw + wn * DDIM + e4);   // L1/L2-hot
        float4 xv = *(const float4*)(x + (size_t)(blk + rl) * DDIM + e4);
        *(float4*)(out_q + (size_t)(blk + rl) * DDIM + e4) = q;  // dense store
        if (!f) {
            float d0 = q.x - xv.x, d1 = q.y - xv.y;
            float d2 = q.z - xv.z, d3 = q.w - xv.w;
            ls += d0 * d0 + d1 * d1 + d2 * d2 + d3 * d3;
        }
    }
    #pragma unroll
    for (int off = 32; off > 0; off >>= 1) ls += __shfl_down(ls, off, 64);
    if (lane == 0) red[w] = ls;
    __syncthreads();   // also orders phase-B stores before phase-C rewrites
    if (tid == 0)
        atomicAdd(out_loss, ((red[0] + red[1]) + (red[2] + red[3])) * LOSS_SCALE);

    // ---- phase C: fused exact-fp32 rescan of flagged rows ----
    const unsigned cnt = lcnt;
    const int grp = tid >> 4;
    const int tx  = tid & 15;
    for (unsigned i = (unsigned)grp; i < cnt; i += 16) {
        const int rl = lslist[i];
        const size_t row = (size_t)blk + rl;

        float4 xr[16];
        const float4* xg = (const float4*)(x + row * DDIM);
        #pragma unroll
        for (int t = 0; t < 16; ++t) xr[t] = xg[t];

        float best = 3.402823466e38f; int bi = 0;
        for (int j = 0; j < 32; ++j) {
            int n = tx + 16 * j;                     // ascending per lane
            const float4* c = (const float4*)(cw + n * DDIM);
            float a0 = 0.f, a1 = 0.f, a2 = 0.f, a3 = 0.f;
            #pragma unroll
            for (int t = 0; t < 16; ++t) {
                float4 cv = c[t];
                a0 = __builtin_fmaf(xr[t].x, cv.x, a0);
                a1 = __builtin_fmaf(xr[t].y, cv.y, a1);
                a2 = __builtin_fmaf(xr[t].z, cv.z, a2);
                a3 = __builtin_fmaf(xr[t].w, cv.w, a3);
            }
            float sc = __builtin_fmaf(-2.f, (a0 + a1) + (a2 + a3), csq[n]);
            if (sc < best) { best = sc; bi = n; }
        }
        #pragma unroll
        for (int off = 8; off > 0; off >>= 1) {
            float d2 = __shfl_down(best, off, 16);
            int   i2 = __shfl_down(bi,   off, 16);
            if (d2 < best || (d2 == best && i2 < bi)) { best = d2; bi = i2; }
        }
        if (tx == 0) {
            out_idx[row] = (float)bi;
            const float4* qg = (const float4*)(cw + bi * DDIM);
            float4* og = (float4*)(out_q + row * DDIM);
            float lf = 0.f;
            #pragma unroll
            for (int t = 0; t < 16; ++t) {
                float4 q = qg[t];
                og[t] = q;
                float d0 = q.x - xr[t].x, d1 = q.y - xr[t].y;
                float d2_ = q.z - xr[t].z, d3 = q.w - xr[t].w;
                lf += d0 * d0 + d1 * d1 + d2_ * d2_ + d3 * d3;
            }
            atomicAdd(out_loss, lf * LOSS_SCALE);
        }
    }
}

extern "C" void kernel_launch(void* const* d_in, const int* in_sizes, int n_in,
                              void* d_out, int out_size, void* d_ws, size_t ws_size,
                              hipStream_t stream) {
    const float* x  = (const float*)d_in[0];   // (64,4096,64) fp32
    const float* cw = (const float*)d_in[1];   // (512,64) fp32
    float* out      = (float*)d_out;
    float* out_q    = out;                      // 16777216
    float* out_idx  = out + 16777216;           // 262144
    float* out_loss = out + 16777216 + 262144;  // 1

    char* ws = (char*)d_ws;
    float*    csq   = (float*)(ws + WS_CSQ);
    float*    csqh  = (float*)(ws + WS_CSQH);
    _Float16* cw_hl = (_Float16*)(ws + WS_HL);

    prep_kernel<<<2, 256, 0, stream>>>(cw, csq, csqh, cw_hl, out_loss);
    vq_mfma_kernel<<<NBLK, 256, 0, stream>>>(x, cw, cw_hl, csqh, csq,
                                             out_q, out_idx, out_loss);
}

// Round 9
// 217.014 us; speedup vs baseline: 3.3921x; 3.3921x over previous
//
#include <hip/hip_runtime.h>

// VQ: N=262144 vectors (64x4096), D=64, K=512 codewords, fp32.
// out (float32): quantized[16777216] | indices[262144] (as float) | loss[1]
//
// R17 = the untested clean cell: 256-thr + 21 KB LDS + NATURAL regalloc.
//  Spill/clean boundary mapped over R10-R16:
//   - spill triggers: forced VGPR cap (R13:40), +32-reg prefetch block
//     (R16), full t-unroll + double acc chain (R14). Allocator pins ~64
//     VGPR and spills rather than growing; scratch also suppresses
//     residency (R14 28.6% occ despite 21 KB LDS).
//   - clean: R10 (no launch_bounds, VGPR 52, 3 blocks/CU, 124us BEST),
//     R12/R15 (unroll 2, single chain, VGPR 64, FETCH 66/WRITE 70 MB).
//   - occupancy: dur tracks waves/SIMD (2->147..158, 3->124); R13 proved
//     6 blocks/CU resident at 21 KB LDS.
//  R17: R15's proven-clean inner loop VERBATIM (CHUNK=64, unroll 2,
//  single acc chain), 256-thr blocks, BROWS=128, grid 2048, NO
//  launch_bounds, cw_hl pure-copy staging (transient regs only).
//  LDS ~20.7 KB -> 6 blocks/CU = 6 waves/SIMD, no spill triggers present.
// Verified-correct conventions (R8-R16 absmax 0):
//   A-frag: A[m=lane&15][k=quad*8+j]; B-frag: B[n=lane&15][k=quad*8+j];
//   C/D:    col=lane&15 (codeword), row=quad*4+reg (x-row).

typedef _Float16 half8 __attribute__((ext_vector_type(8)));
typedef float    floatx4 __attribute__((ext_vector_type(4)));

#define NVEC  262144
#define DDIM  64
#define KCW   512
#define LOSS_SCALE (0.25f / 16777216.0f)
#define DMARGIN 0.005f
#define BROWS 128
#define NBLK  (NVEC / BROWS)     // 2048
#define CHUNK 64                 // codewords per LDS chunk (8 chunks)

// d_ws layout (re-poisoned every call -> prep rewrites everything):
#define WS_CSQ   0          // f32[512]
#define WS_CSQH  2048       // f32[512]  (0.5*csq)
#define WS_HL    8192       // f16[512*128]: row n = hi[64] | lo[64] (256 B)

__global__ void prep_kernel(const float* __restrict__ cw,
                            float* __restrict__ csq,
                            float* __restrict__ csqh,
                            _Float16* __restrict__ cw_hl,
                            float* __restrict__ loss_slot) {
    int n = blockIdx.x * blockDim.x + threadIdx.x;
    if (n < KCW) {
        const float4* r = (const float4*)(cw + n * DDIM);
        _Float16* orow = cw_hl + n * 128;
        float s = 0.f;
        #pragma unroll
        for (int t = 0; t < 8; ++t) {
            float4 a = r[2 * t], b = r[2 * t + 1];
            half8 hh, ll;
            #pragma unroll
            for (int i = 0; i < 4; ++i) {
                float v = ((const float*)&a)[i];
                s += v * v;
                _Float16 h = (_Float16)v;
                hh[i] = h; ll[i] = (_Float16)(v - (float)h);
                v = ((const float*)&b)[i];
                s += v * v;
                h = (_Float16)v;
                hh[4 + i] = h; ll[4 + i] = (_Float16)(v - (float)h);
            }
            *(half8*)(orow + 8 * t) = hh;
            *(half8*)(orow + 64 + 8 * t) = ll;
        }
        csq[n]  = s;
        csqh[n] = 0.5f * s;
    }
    if (n == 0) *loss_slot = 0.f;
}

__global__ void vq_mfma_kernel(const float* __restrict__ x,
                               const float* __restrict__ cw,
                               const _Float16* __restrict__ cw_hl,
                               const float* __restrict__ csqh,
                               const float* __restrict__ csq,
                               float* __restrict__ out_q,
                               float* __restrict__ out_idx,
                               float* __restrict__ out_loss) {
    __shared__ _Float16      Bs[CHUNK * 136];   // 17408 B: [cw][hi64|lo64] pad
    __shared__ float         csqhs[KCW];        // 2048 B (negated 0.5*csq)
    __shared__ int           win[BROWS];
    __shared__ int           lslist[BROWS];
    __shared__ unsigned char flg[BROWS];
    __shared__ float         red[4];
    __shared__ unsigned      lcnt;

    const int tid  = threadIdx.x;
    const int w    = tid >> 6;
    const int lane = tid & 63;
    const int quad = lane >> 4;
    const int col  = lane & 15;
    const int blk  = blockIdx.x * BROWS;

    if (tid == 0) lcnt = 0u;
    csqhs[tid]       = -csqh[tid];
    csqhs[tid + 256] = -csqh[tid + 256];

    // ---- a-frags: 2 row-tiles/wave (32 rows), hi/lo split, in-register ----
    half8 ah0[2], ah1[2], al0[2], al1[2];
    #pragma unroll
    for (int rt = 0; rt < 2; ++rt) {
        const float* xr = x + (size_t)(blk + w * 32 + rt * 16 + col) * DDIM;
        float4 f0 = *(const float4*)(xr + quad * 8);
        float4 f1 = *(const float4*)(xr + quad * 8 + 4);
        float4 g0 = *(const float4*)(xr + 32 + quad * 8);
        float4 g1 = *(const float4*)(xr + 32 + quad * 8 + 4);
        #pragma unroll
        for (int i = 0; i < 4; ++i) {
            float v = ((const float*)&f0)[i];
            _Float16 h = (_Float16)v;
            ah0[rt][i] = h; al0[rt][i] = (_Float16)(v - (float)h);
            v = ((const float*)&f1)[i]; h = (_Float16)v;
            ah0[rt][4 + i] = h; al0[rt][4 + i] = (_Float16)(v - (float)h);
            v = ((const float*)&g0)[i]; h = (_Float16)v;
            ah1[rt][i] = h; al1[rt][i] = (_Float16)(v - (float)h);
            v = ((const float*)&g1)[i]; h = (_Float16)v;
            ah1[rt][4 + i] = h; al1[rt][4 + i] = (_Float16)(v - (float)h);
        }
    }

    float M1[8], M2[8];
    int   idx[8];
    #pragma unroll
    for (int s = 0; s < 8; ++s) {
        M1[s] = -3.402823466e38f; M2[s] = -3.402823466e38f; idx[s] = 0;
    }

    // ---- scan 512 codewords in 8 LDS chunks of 64 ----
    for (int ch = 0; ch < 8; ++ch) {
        __syncthreads();   // prior chunk consumed (first iter: csqhs, lcnt)
        // stage chunk: pure 64 B/thread copy of pre-split rows (transient)
        {
            const int nl  = tid >> 2;            // codeword within chunk
            const int seg = tid & 3;             // 32-half (64 B) segment
            const half8* src =
                (const half8*)(cw_hl + (((size_t)(ch * CHUNK + nl)) << 7) + seg * 32);
            half8* dst = (half8*)(Bs + nl * 136 + seg * 32);
            #pragma unroll
            for (int b = 0; b < 4; ++b) dst[b] = src[b];
        }
        __syncthreads();

        #pragma unroll 2
        for (int t = 0; t < 4; ++t) {
            const int n  = ch * CHUNK + t * 16 + col;
            const int nb = (t * 16 + col) * 136;
            half8 bh0 = *(const half8*)&Bs[nb + quad * 8];
            half8 bh1 = *(const half8*)&Bs[nb + 32 + quad * 8];
            half8 bl0 = *(const half8*)&Bs[nb + 64 + quad * 8];
            half8 bl1 = *(const half8*)&Bs[nb + 96 + quad * 8];
            const float vn = csqhs[n];                   // = -0.5*csq[n]

            #pragma unroll
            for (int rt = 0; rt < 2; ++rt) {
                floatx4 acc = {vn, vn, vn, vn};          // bias folded into C
                acc = __builtin_amdgcn_mfma_f32_16x16x32_f16(ah0[rt], bh0, acc, 0, 0, 0);
                acc = __builtin_amdgcn_mfma_f32_16x16x32_f16(ah1[rt], bh1, acc, 0, 0, 0);
                acc = __builtin_amdgcn_mfma_f32_16x16x32_f16(al0[rt], bh0, acc, 0, 0, 0);
                acc = __builtin_amdgcn_mfma_f32_16x16x32_f16(al1[rt], bh1, acc, 0, 0, 0);
                acc = __builtin_amdgcn_mfma_f32_16x16x32_f16(ah0[rt], bl0, acc, 0, 0, 0);
                acc = __builtin_amdgcn_mfma_f32_16x16x32_f16(ah1[rt], bl1, acc, 0, 0, 0);
                #pragma unroll
                for (int reg = 0; reg < 4; ++reg) {
                    int s = rt * 4 + reg;
                    float d = acc[reg];                  // dot - 0.5*csq (max)
                    if (d > M1[s]) idx[s] = n;           // strict >: first-max
                    M2[s] = __builtin_amdgcn_fmed3f(M1[s], M2[s], d);
                    M1[s] = fmaxf(M1[s], d);
                }
            }
        }
    }

    // ---- cross-lane (M1, idx, M2) reduce over the 16 cols of each quad ----
    #pragma unroll
    for (int off = 1; off < 16; off <<= 1) {
        #pragma unroll
        for (int s = 0; s < 8; ++s) {
            float o1 = __shfl_xor(M1[s], off, 16);
            float o2 = __shfl_xor(M2[s], off, 16);
            int   oi = __shfl_xor(idx[s], off, 16);
            float mn = fminf(M1[s], o1);             // loser of the two leaders
            M2[s] = fmaxf(fmaxf(M2[s], o2), mn);
            if (o1 > M1[s] || (o1 == M1[s] && oi < idx[s])) idx[s] = oi;
            M1[s] = fmaxf(M1[s], o1);
        }
    }

    // ---- phase A: winners, flags, block-local flagged list ----
    if (col < 4) {   // lane col handles reg=col for both row-tiles
        #pragma unroll
        for (int rt = 0; rt < 2; ++rt) {
            int s  = rt * 4 + col;
            int rl = w * 32 + rt * 16 + quad * 4 + col;
            int nw = idx[s];
            int f  = (M1[s] - M2[s] <= DMARGIN) ? 1 : 0;
            win[rl] = nw;
            flg[rl] = (unsigned char)f;
            out_idx[blk + rl] = (float)nw;           // flagged rows fixed below
            if (f) { unsigned p = atomicAdd(&lcnt, 1u); lslist[p] = rl; }
        }
    }
    __syncthreads();

    // ---- phase B: dense quantized write + commitment loss (skip flagged) ----
    float ls = 0.f;
    #pragma unroll
    for (int k = 0; k < 8; ++k) {
        int rl = k * 16 + (tid >> 4);
        int e4 = (tid & 15) * 4;                     // lane-contiguous 16 B
        int wn = win[rl];
        int f  = flg[rl];
        float4 q  = *(const float4*)(cw + wn * DDIM + e4);   // L1/L2-hot
        float4 xv = *(const float4*)(x + (size_t)(blk + rl) * DDIM + e4);
        *(float4*)(out_q + (size_t)(blk + rl) * DDIM + e4) = q;  // dense store
        if (!f) {
            float d0 = q.x - xv.x, d1 = q.y - xv.y;
            float d2 = q.z - xv.z, d3 = q.w - xv.w;
            ls += d0 * d0 + d1 * d1 + d2 * d2 + d3 * d3;
        }
    }
    #pragma unroll
    for (int off = 32; off > 0; off >>= 1) ls += __shfl_down(ls, off, 64);
    if (lane == 0) red[w] = ls;
    __syncthreads();   // also orders phase-B stores before phase-C rewrites
    if (tid == 0)
        atomicAdd(out_loss, ((red[0] + red[1]) + (red[2] + red[3])) * LOSS_SCALE);

    // ---- phase C: fused exact-fp32 rescan of flagged rows ----
    const unsigned cnt = lcnt;
    const int grp = tid >> 4;
    const int tx  = tid & 15;
    for (unsigned i = (unsigned)grp; i < cnt; i += 16) {
        const int rl = lslist[i];
        const size_t row = (size_t)blk + rl;

        float4 xr[16];
        const float4* xg = (const float4*)(x + row * DDIM);
        #pragma unroll
        for (int t = 0; t < 16; ++t) xr[t] = xg[t];

        float best = 3.402823466e38f; int bi = 0;
        for (int j = 0; j < 32; ++j) {
            int n = tx + 16 * j;                     // ascending per lane
            const float4* c = (const float4*)(cw + n * DDIM);
            float a0 = 0.f, a1 = 0.f, a2 = 0.f, a3 = 0.f;
            #pragma unroll
            for (int t = 0; t < 16; ++t) {
                float4 cv = c[t];
                a0 = __builtin_fmaf(xr[t].x, cv.x, a0);
                a1 = __builtin_fmaf(xr[t].y, cv.y, a1);
                a2 = __builtin_fmaf(xr[t].z, cv.z, a2);
                a3 = __builtin_fmaf(xr[t].w, cv.w, a3);
            }
            float sc = __builtin_fmaf(-2.f, (a0 + a1) + (a2 + a3), csq[n]);
            if (sc < best) { best = sc; bi = n; }
        }
        #pragma unroll
        for (int off = 8; off > 0; off >>= 1) {
            float d2 = __shfl_down(best, off, 16);
            int   i2 = __shfl_down(bi,   off, 16);
            if (d2 < best || (d2 == best && i2 < bi)) { best = d2; bi = i2; }
        }
        if (tx == 0) {
            out_idx[row] = (float)bi;
            const float4* qg = (const float4*)(cw + bi * DDIM);
            float4* og = (float4*)(out_q + row * DDIM);
            float lf = 0.f;
            #pragma unroll
            for (int t = 0; t < 16; ++t) {
                float4 q = qg[t];
                og[t] = q;
                float d0 = q.x - xr[t].x, d1 = q.y - xr[t].y;
                float d2_ = q.z - xr[t].z, d3 = q.w - xr[t].w;
                lf += d0 * d0 + d1 * d1 + d2_ * d2_ + d3 * d3;
            }
            atomicAdd(out_loss, lf * LOSS_SCALE);
        }
    }
}

extern "C" void kernel_launch(void* const* d_in, const int* in_sizes, int n_in,
                              void* d_out, int out_size, void* d_ws, size_t ws_size,
                              hipStream_t stream) {
    const float* x  = (const float*)d_in[0];   // (64,4096,64) fp32
    const float* cw = (const float*)d_in[1];   // (512,64) fp32
    float* out      = (float*)d_out;
    float* out_q    = out;                      // 16777216
    float* out_idx  = out + 16777216;           // 262144
    float* out_loss = out + 16777216 + 262144;  // 1

    char* ws = (char*)d_ws;
    float*    csq   = (float*)(ws + WS_CSQ);
    float*    csqh  = (float*)(ws + WS_CSQH);
    _Float16* cw_hl = (_Float16*)(ws + WS_HL);

    prep_kernel<<<2, 256, 0, stream>>>(cw, csq, csqh, cw_hl, out_loss);
    vq_mfma_kernel<<<NBLK, 256, 0, stream>>>(x, cw, cw_hl, csqh, csq,
                                             out_q, out_idx, out_loss);
}